// Round 9
// baseline (203.405 us; speedup 1.0000x reference)
//
#include <hip/hip_runtime.h>
#include <cstdint>
#include <cstddef>

// ---------------------------------------------------------------------------
// Plant_Identifier CNN forward.
// R9: conv1 staging conversion hoisted into one streaming prep kernel
//     (d fp32 planar -> 16B hi/lo records); conv1 reads B-fragments directly
//     from rec via coalesced 16B global loads (no LDS, no syncthreads).
//     rec aliases the X2..MX3 region (dead until conv2).
// R8: BN+ReLU+maxpool commuted past the affine: convs emit RAW pooled
//     max+min; tiny bnrelu kernels apply BN after stats finalize.
// conv1: bf16 MFMA with hi/lo split (fp32-exact). conv2/3: bf16 MFMA
// implicit-GEMM, fused stats + raw pool. fc1: zero-LDS MFMA K-split GEMM.
// All reductions deterministic (fixed-order two-stage partials).
// ---------------------------------------------------------------------------

typedef __attribute__((ext_vector_type(8))) short sh8_t;   // 8 x bf16
typedef __attribute__((ext_vector_type(4))) float f4_t;    // mfma acc
typedef unsigned short u16;
typedef unsigned int u32;

// workspace layout (float units)
#define WS_X1   ((size_t)0)          // x1  bf16 [64,112,112,16]  (6,422,528)
#define WS_MX1  ((size_t)6422528)    // mx1 bf16 [64,112,112,16]  (6,422,528)
#define WS_MN1  ((size_t)12845056)   // mn1                        (6,422,528)
#define WS_X2   ((size_t)19267584)   // x2  bf16 [64,56,56,32]    (3,211,264)
#define WS_MX2  ((size_t)22478848)   // mx2                        (3,211,264)
#define WS_MN2  ((size_t)25690112)   // mn2                        (3,211,264)
#define WS_X3T  ((size_t)28901376)   // x3t bf16 [64,64,28,28]    (1,605,632)
#define WS_MX3  ((size_t)30507008)   // mx3 bf16 [64,28,28,64]    (1,605,632)
#define WS_MN3  ((size_t)32112640)   // mn3                        (1,605,632)
// rec bf16 [64,224,224,8] = 25,690,112 u16 = 12,845,056 slots: ALIASES
// [WS_X2, WS_MN3) — rec is dead before conv2 first writes X2/MX2/MN2.
#define WS_REC  WS_X2
#define WS_WT1  ((size_t)33718272)   // 512
#define WS_WT2  ((size_t)33718784)   // 3,072
#define WS_WT3  ((size_t)33721856)   // 9,216
#define WS_P1   ((size_t)33731072)   // 16*2*57600 = 1,843,200
#define WS_P2   ((size_t)35574272)   // 32*2*12544 = 802,816
#define WS_P3   ((size_t)36377088)   // 64*2*3584  = 458,752
#define WS_PD   ((size_t)36835840)   // 4,096
#define WS_ST   ((size_t)36839936)   // 224
#define WS_FCP  ((size_t)36840160)   // 917,504
#define WS_H1   ((size_t)37757664)   // 16,384
// total 37,774,048 floats = 151.1 MB

static __device__ __forceinline__ float4 ldg4(const float* p) {
  return *reinterpret_cast<const float4*>(p);
}
static __device__ __forceinline__ float bf2f(u16 u) {
  union { u32 i; float f; } c; c.i = ((u32)u) << 16; return c.f;
}
static __device__ __forceinline__ u16 f2bf(float f) {
  union { float f; u32 i; } c; c.f = f;
  const u32 x = c.i;
  return (u16)((x + 0x7fffu + ((x >> 16) & 1u)) >> 16);   // RNE
}

// ---------------- weight prep -----------------------------------------------
__global__ __launch_bounds__(256)
void k_prep_w(const float* __restrict__ w1, const float* __restrict__ w2,
              const float* __restrict__ w3, u16* __restrict__ wt1,
              u16* __restrict__ wt2, u16* __restrict__ wt3) {
  const int t = blockIdx.x * 256 + threadIdx.x;  // 25600 total
  if (t < 1024) {
    const int half = t >> 9;
    const int u = t & 511;
    const int co = u >> 5, k = u & 31;
    const int g = k >> 3, j = k & 7;
    const int kh = g >> 1, kw = g & 1;
    const int ci = (j < 4) ? j : j - 4;
    bool active = (j != 3) && (j != 7);
    if (half == 1) active = active && (j < 4);
    float val = 0.f;
    if (active) {
      const float w = w1[((co * 3 + ci) * 2 + kh) * 2 + kw];
      const u16 h = f2bf(w);
      val = (half == 0) ? bf2f(h) : (w - bf2f(h));
    }
    wt1[t] = f2bf(val);
  } else if (t < 7168) {  // wt2 [co32][kh3][kwp4][ci16], kw=3 zero-padded
    const int u = t - 1024;
    const int ci = u & 15, kwp = (u >> 4) & 3, kh = (u >> 6) % 3, co = u / 192;
    float v = 0.f;
    if (kwp < 3) v = w2[((co * 16 + ci) * 3 + kh) * 3 + kwp];
    wt2[u] = f2bf(v);
  } else {                // wt3 [co64][kh3][kw3][ci32]
    const int u = t - 7168;
    const int ci = u & 31, kw = (u >> 5) % 3, kh = (u / 96) % 3, co = u / 288;
    wt3[u] = f2bf(w3[((co * 32 + ci) * 3 + kh) * 3 + kw]);
  }
}

// ---------------- input prep: planar fp32 -> 16B hi/lo records --------------
// thread = 4 consecutive px of one row. 3136 blocks x 256 thr.
__global__ __launch_bounds__(256)
void k_prep_rec(const float* __restrict__ d, u16* __restrict__ rec) {
  const int t = blockIdx.x * 256 + threadIdx.x;   // 802,816
  const int px4 = t * 4;                          // (n*50176 + ih*224 + iw)
  const int n = px4 / 50176;
  const int remn = px4 - n * 50176;
  const float4 v0 = ldg4(d + (size_t)(n * 3 + 0) * 50176 + remn);
  const float4 v1 = ldg4(d + (size_t)(n * 3 + 1) * 50176 + remn);
  const float4 v2 = ldg4(d + (size_t)(n * 3 + 2) * 50176 + remn);
  const float* c0 = reinterpret_cast<const float*>(&v0);
  const float* c1 = reinterpret_cast<const float*>(&v1);
  const float* c2 = reinterpret_cast<const float*>(&v2);
  #pragma unroll
  for (int i = 0; i < 4; ++i) {
    const float a = c0[i], b = c1[i], c = c2[i];
    const u16 h0 = f2bf(a), h1 = f2bf(b), h2 = f2bf(c);
    const u16 l0 = f2bf(a - bf2f(h0));
    const u16 l1 = f2bf(b - bf2f(h1));
    const u16 l2 = f2bf(c - bf2f(h2));
    int4 r;
    r.x = (u32)h0 | ((u32)h1 << 16);
    r.y = (u32)h2;
    r.z = (u32)l0 | ((u32)l1 << 16);
    r.w = (u32)l2;
    *reinterpret_cast<int4*>(rec + (size_t)(px4 + i) * 8) = r;
  }
}

// ---------------- conv1 MFMA: no LDS, direct record loads -------------------
// grid (15,15,64), 256 thr. 16x16 output tile of the 225x225 pre-pool map.
// lane (g,li): tap (kh=g>>1, kw=g&1); B = rec[(oh-1+kh, ow-1+kw)] (16B).
__global__ __launch_bounds__(256)
void k_conv1(const u16* __restrict__ rec, const u16* __restrict__ wt1,
             const float* __restrict__ b1, u16* __restrict__ mx1,
             u16* __restrict__ mn1, float* __restrict__ part) {
  const int bx = blockIdx.x, by = blockIdx.y, n = blockIdx.z;
  const int ow0 = bx * 16, oh0 = by * 16;
  const int t = threadIdx.x, lane = t & 63, wv = t >> 6;
  const int g = lane >> 4, li = lane & 15;
  const int kh = g >> 1, kw = g & 1;
  const sh8_t A1 = *reinterpret_cast<const sh8_t*>(wt1 + li * 32 + g * 8);
  const sh8_t A2 = *reinterpret_cast<const sh8_t*>(wt1 + 512 + li * 32 + g * 8);
  const int iw = ow0 + li + kw - 1;
  const bool iwv = (unsigned)iw < 224u;
  f4_t acc[4];
  #pragma unroll
  for (int r = 0; r < 4; ++r) acc[r] = (f4_t)0.f;
  #pragma unroll
  for (int r = 0; r < 4; ++r) {
    const int ih = oh0 + wv * 4 + r + kh - 1;
    sh8_t B = (sh8_t)(short)0;
    if (iwv && (unsigned)ih < 224u)
      B = *reinterpret_cast<const sh8_t*>(rec + ((size_t)(n * 224 + ih) * 224 + iw) * 8);
    acc[r] = __builtin_amdgcn_mfma_f32_16x16x32_bf16(A1, B, acc[r], 0, 0, 0);
    acc[r] = __builtin_amdgcn_mfma_f32_16x16x32_bf16(A2, B, acc[r], 0, 0, 0);
  }
  // D: col = li (pixel ow), row = 4g+j (co). y = acc + bias.
  const f4_t bias = *reinterpret_cast<const f4_t*>(b1 + 4 * g);
  f4_t y[4];
  #pragma unroll
  for (int r = 0; r < 4; ++r) y[r] = acc[r] + bias;
  const int ow = ow0 + li;
  // stats over valid 225x225
  {
    f4_t ssum = (f4_t)0.f, ssq = (f4_t)0.f;
    #pragma unroll
    for (int r = 0; r < 4; ++r) {
      const int oh = oh0 + wv * 4 + r;
      if (oh <= 224 && ow <= 224) { ssum += y[r]; ssq += y[r] * y[r]; }
    }
    #pragma unroll
    for (int m = 1; m < 16; m <<= 1)
      #pragma unroll
      for (int j = 0; j < 4; ++j) {
        ssum[j] += __shfl_xor(ssum[j], m);
        ssq[j]  += __shfl_xor(ssq[j], m);
      }
    if (li == 0) {
      const int slot = ((n * 15 + by) * 15 + bx) * 4 + wv;  // P1 = 57600
      #pragma unroll
      for (int j = 0; j < 4; ++j) {
        part[(size_t)((4 * g + j) * 2 + 0) * 57600 + slot] = ssum[j];
        part[(size_t)((4 * g + j) * 2 + 1) * 57600 + slot] = ssq[j];
      }
    }
  }
  // raw 2x2 max/min pool (224x224 region only)
  if (bx < 14 && by < 14) {
    #pragma unroll
    for (int rp = 0; rp < 2; ++rp) {
      f4_t vmax, vmin;
      #pragma unroll
      for (int j = 0; j < 4; ++j) {
        vmax[j] = fmaxf(y[2 * rp][j], y[2 * rp + 1][j]);
        vmin[j] = fminf(y[2 * rp][j], y[2 * rp + 1][j]);
      }
      f4_t omx, omn;
      #pragma unroll
      for (int j = 0; j < 4; ++j) {
        omx[j] = __shfl_xor(vmax[j], 1);
        omn[j] = __shfl_xor(vmin[j], 1);
      }
      if ((li & 1) == 0) {
        const int po = 8 * by + 2 * wv + rp, qo = 8 * bx + (li >> 1);
        const size_t off = ((size_t)((n * 112 + po) * 112 + qo)) * 16 + 4 * g;
        uint2 pmx, pmn;
        pmx.x = (u32)f2bf(fmaxf(vmax[0], omx[0])) | ((u32)f2bf(fmaxf(vmax[1], omx[1])) << 16);
        pmx.y = (u32)f2bf(fmaxf(vmax[2], omx[2])) | ((u32)f2bf(fmaxf(vmax[3], omx[3])) << 16);
        pmn.x = (u32)f2bf(fminf(vmin[0], omn[0])) | ((u32)f2bf(fminf(vmin[1], omn[1])) << 16);
        pmn.y = (u32)f2bf(fminf(vmin[2], omn[2])) | ((u32)f2bf(fminf(vmin[3], omn[3])) << 16);
        *reinterpret_cast<uint2*>(mx1 + off) = pmx;
        *reinterpret_cast<uint2*>(mn1 + off) = pmn;
      }
    }
  }
}

// ------------- BN finalize stage 1: parallel chunk reduce -------------------
__global__ __launch_bounds__(256)
void k_fin1(const float* __restrict__ part, int P, int chunk, int S,
            double* __restrict__ p2) {
  const int c = blockIdx.x, s = blockIdx.y;
  const int start = s * chunk;
  const int end = min(P, start + chunk);
  __shared__ double rs[256], rq[256];
  double accs[2];
  #pragma unroll
  for (int mom = 0; mom < 2; ++mom) {
    const float* base = part + (size_t)(c * 2 + mom) * P;
    double a0 = 0.0, a1 = 0.0, a2 = 0.0, a3 = 0.0;
    int i = start + threadIdx.x * 4;
    for (; i + 3 < end; i += 1024) {
      const float4 v = ldg4(base + i);
      a0 += v.x; a1 += v.y; a2 += v.z; a3 += v.w;
    }
    for (int j = i; j < end && j < i + 4; ++j) a0 += base[j];
    accs[mom] = (a0 + a1) + (a2 + a3);
  }
  rs[threadIdx.x] = accs[0]; rq[threadIdx.x] = accs[1];
  __syncthreads();
  for (int off = 128; off > 0; off >>= 1) {
    if (threadIdx.x < off) {
      rs[threadIdx.x] += rs[threadIdx.x + off];
      rq[threadIdx.x] += rq[threadIdx.x + off];
    }
    __syncthreads();
  }
  if (threadIdx.x == 0) {
    p2[(size_t)(c * 2 + 0) * S + s] = rs[0];
    p2[(size_t)(c * 2 + 1) * S + s] = rq[0];
  }
}

// ------------- BN finalize stage 2 ------------------------------------------
__global__ __launch_bounds__(64)
void k_fin2(const double* __restrict__ p2, int S, double count,
            const float* __restrict__ g, const float* __restrict__ bta,
            float* __restrict__ scale, float* __restrict__ shift) {
  const int c = blockIdx.x, t = threadIdx.x;
  double s = 0.0, sq = 0.0;
  if (t < S) {
    s  = p2[(size_t)(c * 2 + 0) * S + t];
    sq = p2[(size_t)(c * 2 + 1) * S + t];
  }
  #pragma unroll
  for (int m = 1; m < 64; m <<= 1) {
    s  += __shfl_xor(s, m);
    sq += __shfl_xor(sq, m);
  }
  if (t == 0) {
    const double mean = s / count;
    const double var  = sq / count - mean * mean;
    const double rstd = 1.0 / sqrt(var + 1e-5);
    const double sc = (double)g[c] * rstd;
    scale[c] = (float)sc;
    shift[c] = (float)((double)bta[c] - mean * sc);
  }
}

// ------------- bnrelu: x = relu(sc*(sc>=0?mx:mn) + sh), NHWC ----------------
template<int CH, int P>
__global__ __launch_bounds__(256)
void k_bnrelu(const u16* __restrict__ mx, const u16* __restrict__ mn,
              const float* __restrict__ scale, const float* __restrict__ shift,
              u16* __restrict__ xout) {
  constexpr int G = CH / 8;
  const int idx = blockIdx.x * 256 + threadIdx.x;
  const int cg = idx & (G - 1);
  int rest = idx / G;
  const int qo = rest % P; rest /= P;
  const int po = rest % P;
  const int n = rest / P;
  const size_t base = ((size_t)((n * P + po) * P + qo)) * CH + cg * 8;
  const int4 vmx = *reinterpret_cast<const int4*>(mx + base);
  const int4 vmn = *reinterpret_cast<const int4*>(mn + base);
  const u32* am = reinterpret_cast<const u32*>(&vmx);
  const u32* an = reinterpret_cast<const u32*>(&vmn);
  u16 o[8];
  #pragma unroll
  for (int j = 0; j < 8; ++j) {
    const int c = cg * 8 + j;
    const float sc = scale[c], sh = shift[c];
    const u32 src = (sc >= 0.f) ? am[j >> 1] : an[j >> 1];
    const u16 raw = (u16)(src >> ((j & 1) * 16));
    o[j] = f2bf(fmaxf(fmaf(bf2f(raw), sc, sh), 0.f));
  }
  u32 pk[4];
  #pragma unroll
  for (int k = 0; k < 4; ++k) pk[k] = (u32)o[2 * k] | ((u32)o[2 * k + 1] << 16);
  *reinterpret_cast<int4*>(xout + base) = make_int4(pk[0], pk[1], pk[2], pk[3]);
}

// ------------- conv2: bf16 MFMA + stats + raw pool ---------------------------
__global__ __launch_bounds__(256)
void k_conv2(const u16* __restrict__ x1, const u16* __restrict__ wt2,
             const float* __restrict__ b2, u16* __restrict__ mx2,
             u16* __restrict__ mn2, float* __restrict__ part) {
  const int ow0 = blockIdx.x * 16, oh0 = blockIdx.y * 16, n = blockIdx.z;
  const int t = threadIdx.x, lane = t & 63, wv = t >> 6;
  const int g = lane >> 4, li = lane & 15;
  __shared__ __align__(16) unsigned char tile[18 * 640];
  for (int idx = t; idx < 720; idx += 256) {
    const int rr = idx / 40, rem = idx - rr * 40, p = rem >> 1, c = rem & 1;
    const int ih = oh0 - 1 + rr, iw = ow0 - 1 + p;
    int4 v = make_int4(0, 0, 0, 0);
    if ((unsigned)ih < 112u && (unsigned)iw < 112u)
      v = *reinterpret_cast<const int4*>(x1 + ((size_t)((n * 112 + ih) * 112 + iw) * 16 + c * 8));
    *reinterpret_cast<int4*>(tile + ((rr * 640 + p * 32 + c * 16) ^ (((p >> 2) & 1) << 4))) = v;
  }
  sh8_t W[2][3][2];
  #pragma unroll
  for (int cot = 0; cot < 2; ++cot)
    #pragma unroll
    for (int kh = 0; kh < 3; ++kh)
      #pragma unroll
      for (int m = 0; m < 2; ++m)
        W[cot][kh][m] = *reinterpret_cast<const sh8_t*>(
            wt2 + ((cot * 16 + li) * 192 + kh * 64 + m * 32 + g * 8));
  f4_t acc[4][2];
  #pragma unroll
  for (int r = 0; r < 4; ++r) { acc[r][0] = (f4_t)0.f; acc[r][1] = (f4_t)0.f; }
  __syncthreads();
  const int rowb = 4 * wv;
  #pragma unroll
  for (int ihr = 0; ihr < 6; ++ihr) {
    const int row = rowb + ihr;
    #pragma unroll
    for (int m = 0; m < 2; ++m) {
      const int p = li + 2 * m + (g >> 1);
      const sh8_t B = *reinterpret_cast<const sh8_t*>(
          tile + ((row * 640 + p * 32 + (g & 1) * 16) ^ (((p >> 2) & 1) << 4)));
      #pragma unroll
      for (int kh = 0; kh < 3; ++kh) {
        const int r = ihr - kh;
        if (r >= 0 && r < 4) {
          acc[r][0] = __builtin_amdgcn_mfma_f32_16x16x32_bf16(W[0][kh][m], B, acc[r][0], 0, 0, 0);
          acc[r][1] = __builtin_amdgcn_mfma_f32_16x16x32_bf16(W[1][kh][m], B, acc[r][1], 0, 0, 0);
        }
      }
    }
  }
  f4_t bias[2], ssum[2], ssq[2];
  bias[0] = *reinterpret_cast<const f4_t*>(b2 + 4 * g);
  bias[1] = *reinterpret_cast<const f4_t*>(b2 + 16 + 4 * g);
  ssum[0] = (f4_t)0.f; ssum[1] = (f4_t)0.f; ssq[0] = (f4_t)0.f; ssq[1] = (f4_t)0.f;
  #pragma unroll
  for (int r = 0; r < 4; ++r)
    #pragma unroll
    for (int cot = 0; cot < 2; ++cot) {
      acc[r][cot] += bias[cot];
      ssum[cot] += acc[r][cot];
      ssq[cot] += acc[r][cot] * acc[r][cot];
    }
  #pragma unroll
  for (int msk = 1; msk < 16; msk <<= 1)
    #pragma unroll
    for (int cot = 0; cot < 2; ++cot)
      #pragma unroll
      for (int j = 0; j < 4; ++j) {
        ssum[cot][j] += __shfl_xor(ssum[cot][j], msk);
        ssq[cot][j]  += __shfl_xor(ssq[cot][j], msk);
      }
  if (li == 0) {
    const int slot = (((n * 7 + (int)blockIdx.y) * 7 + (int)blockIdx.x)) * 4 + wv;  // 12544
    #pragma unroll
    for (int cot = 0; cot < 2; ++cot)
      #pragma unroll
      for (int j = 0; j < 4; ++j) {
        const int co = cot * 16 + 4 * g + j;
        part[(size_t)(co * 2 + 0) * 12544 + slot] = ssum[cot][j];
        part[(size_t)(co * 2 + 1) * 12544 + slot] = ssq[cot][j];
      }
  }
  const int pob = 8 * (int)blockIdx.y + 2 * wv;
  const int qo = 8 * (int)blockIdx.x + (li >> 1);
  #pragma unroll
  for (int rp = 0; rp < 2; ++rp)
    #pragma unroll
    for (int cot = 0; cot < 2; ++cot) {
      f4_t vmax, vmin;
      #pragma unroll
      for (int j = 0; j < 4; ++j) {
        vmax[j] = fmaxf(acc[2 * rp][cot][j], acc[2 * rp + 1][cot][j]);
        vmin[j] = fminf(acc[2 * rp][cot][j], acc[2 * rp + 1][cot][j]);
      }
      f4_t omx, omn;
      #pragma unroll
      for (int j = 0; j < 4; ++j) {
        omx[j] = __shfl_xor(vmax[j], 1);
        omn[j] = __shfl_xor(vmin[j], 1);
      }
      if ((li & 1) == 0) {
        const size_t off = ((size_t)((n * 56 + pob + rp) * 56 + qo)) * 32 + cot * 16 + 4 * g;
        uint2 pmx, pmn;
        pmx.x = (u32)f2bf(fmaxf(vmax[0], omx[0])) | ((u32)f2bf(fmaxf(vmax[1], omx[1])) << 16);
        pmx.y = (u32)f2bf(fmaxf(vmax[2], omx[2])) | ((u32)f2bf(fmaxf(vmax[3], omx[3])) << 16);
        pmn.x = (u32)f2bf(fminf(vmin[0], omn[0])) | ((u32)f2bf(fminf(vmin[1], omn[1])) << 16);
        pmn.y = (u32)f2bf(fminf(vmin[2], omn[2])) | ((u32)f2bf(fminf(vmin[3], omn[3])) << 16);
        *reinterpret_cast<uint2*>(mx2 + off) = pmx;
        *reinterpret_cast<uint2*>(mn2 + off) = pmn;
      }
    }
}

// ------------- conv3: bf16 MFMA + stats + raw pool ---------------------------
__global__ __launch_bounds__(256)
void k_conv3(const u16* __restrict__ x2, const u16* __restrict__ wt3,
             const float* __restrict__ b3, u16* __restrict__ mx3,
             u16* __restrict__ mn3, float* __restrict__ part) {
  const int ow0 = blockIdx.x * 16, oh0 = blockIdx.y * 8, n = blockIdx.z;
  const int t = threadIdx.x, lane = t & 63, wv = t >> 6;
  const int rh = wv & 1, ch = wv >> 1;
  const int g = lane >> 4, li = lane & 15;
  __shared__ __align__(16) unsigned char tile[10 * 1152];
  for (int idx = t; idx < 720; idx += 256) {
    const int rr = idx / 72, rem = idx - rr * 72, p = rem >> 2, c = rem & 3;
    const int ih = oh0 - 1 + rr, iw = ow0 - 1 + p;
    int4 v = make_int4(0, 0, 0, 0);
    if ((unsigned)ih < 56u && (unsigned)iw < 56u)
      v = *reinterpret_cast<const int4*>(x2 + ((size_t)((n * 56 + ih) * 56 + iw) * 32 + c * 8));
    *reinterpret_cast<int4*>(tile + ((rr * 1152 + p * 64 + c * 16) ^ (((p >> 1) & 3) << 4))) = v;
  }
  sh8_t W[2][3][3];
  #pragma unroll
  for (int c2 = 0; c2 < 2; ++c2)
    #pragma unroll
    for (int kh = 0; kh < 3; ++kh)
      #pragma unroll
      for (int kw = 0; kw < 3; ++kw)
        W[c2][kh][kw] = *reinterpret_cast<const sh8_t*>(
            wt3 + ((size_t)(ch * 32 + c2 * 16 + li) * 288 + (kh * 3 + kw) * 32 + g * 8));
  f4_t acc[4][2];
  #pragma unroll
  for (int r = 0; r < 4; ++r) { acc[r][0] = (f4_t)0.f; acc[r][1] = (f4_t)0.f; }
  __syncthreads();
  const int rowb = 4 * rh;
  #pragma unroll
  for (int ihr = 0; ihr < 6; ++ihr) {
    const int row = rowb + ihr;
    #pragma unroll
    for (int kw = 0; kw < 3; ++kw) {
      const int p = li + kw;
      const sh8_t B = *reinterpret_cast<const sh8_t*>(
          tile + ((row * 1152 + p * 64 + g * 16) ^ (((p >> 1) & 3) << 4)));
      #pragma unroll
      for (int kh = 0; kh < 3; ++kh) {
        const int r = ihr - kh;
        if (r >= 0 && r < 4) {
          acc[r][0] = __builtin_amdgcn_mfma_f32_16x16x32_bf16(W[0][kh][kw], B, acc[r][0], 0, 0, 0);
          acc[r][1] = __builtin_amdgcn_mfma_f32_16x16x32_bf16(W[1][kh][kw], B, acc[r][1], 0, 0, 0);
        }
      }
    }
  }
  const int ow = ow0 + li;
  const bool valid = ow < 56;
  f4_t bias[2], ssum[2], ssq[2];
  bias[0] = *reinterpret_cast<const f4_t*>(b3 + ch * 32 + 4 * g);
  bias[1] = *reinterpret_cast<const f4_t*>(b3 + ch * 32 + 16 + 4 * g);
  ssum[0] = (f4_t)0.f; ssum[1] = (f4_t)0.f; ssq[0] = (f4_t)0.f; ssq[1] = (f4_t)0.f;
  #pragma unroll
  for (int r = 0; r < 4; ++r)
    #pragma unroll
    for (int c2 = 0; c2 < 2; ++c2) {
      acc[r][c2] += bias[c2];
      if (valid) {
        ssum[c2] += acc[r][c2];
        ssq[c2] += acc[r][c2] * acc[r][c2];
      }
    }
  #pragma unroll
  for (int msk = 1; msk < 16; msk <<= 1)
    #pragma unroll
    for (int c2 = 0; c2 < 2; ++c2)
      #pragma unroll
      for (int j = 0; j < 4; ++j) {
        ssum[c2][j] += __shfl_xor(ssum[c2][j], msk);
        ssq[c2][j]  += __shfl_xor(ssq[c2][j], msk);
      }
  if (li == 0) {
    const int slot = (((n * 7 + (int)blockIdx.y) * 4 + (int)blockIdx.x)) * 2 + rh;  // 3584
    #pragma unroll
    for (int c2 = 0; c2 < 2; ++c2)
      #pragma unroll
      for (int j = 0; j < 4; ++j) {
        const int co = ch * 32 + c2 * 16 + 4 * g + j;
        part[(size_t)(co * 2 + 0) * 3584 + slot] = ssum[c2][j];
        part[(size_t)(co * 2 + 1) * 3584 + slot] = ssq[c2][j];
      }
  }
  const int pob = 4 * (int)blockIdx.y + 2 * rh;
  const int qo = 8 * (int)blockIdx.x + (li >> 1);
  #pragma unroll
  for (int rp = 0; rp < 2; ++rp)
    #pragma unroll
    for (int c2 = 0; c2 < 2; ++c2) {
      f4_t vmax, vmin;
      #pragma unroll
      for (int j = 0; j < 4; ++j) {
        vmax[j] = fmaxf(acc[2 * rp][c2][j], acc[2 * rp + 1][c2][j]);
        vmin[j] = fminf(acc[2 * rp][c2][j], acc[2 * rp + 1][c2][j]);
      }
      f4_t omx, omn;
      #pragma unroll
      for (int j = 0; j < 4; ++j) {
        omx[j] = __shfl_xor(vmax[j], 1);
        omn[j] = __shfl_xor(vmin[j], 1);
      }
      if (((li & 1) == 0) && (ow + 1 < 56)) {
        const size_t off = ((size_t)((n * 28 + pob + rp) * 28 + qo)) * 64 + ch * 32 + c2 * 16 + 4 * g;
        uint2 pmx, pmn;
        pmx.x = (u32)f2bf(fmaxf(vmax[0], omx[0])) | ((u32)f2bf(fmaxf(vmax[1], omx[1])) << 16);
        pmx.y = (u32)f2bf(fmaxf(vmax[2], omx[2])) | ((u32)f2bf(fmaxf(vmax[3], omx[3])) << 16);
        pmn.x = (u32)f2bf(fminf(vmin[0], omn[0])) | ((u32)f2bf(fminf(vmin[1], omn[1])) << 16);
        pmn.y = (u32)f2bf(fminf(vmin[2], omn[2])) | ((u32)f2bf(fminf(vmin[3], omn[3])) << 16);
        *reinterpret_cast<uint2*>(mx3 + off) = pmx;
        *reinterpret_cast<uint2*>(mn3 + off) = pmn;
      }
    }
}

// ------------- bnrelu3 + NHWC->NCHW transpose for fc1 -----------------------
__global__ __launch_bounds__(256)
void k_bnrelu3t(const u16* __restrict__ mx3, const u16* __restrict__ mn3,
                const float* __restrict__ scale, const float* __restrict__ shift,
                u16* __restrict__ x3t) {
  const int n = blockIdx.y;
  const int c = threadIdx.x & 63, pq = threadIdx.x >> 6;
  const int po = blockIdx.x * 4 + pq;
  const float sc = scale[c], sh = shift[c];
  const bool useMax = (sc >= 0.f);
  const size_t row0 = ((size_t)(n * 28 + po)) * 28 * 64 + c;
  #pragma unroll
  for (int q4 = 0; q4 < 7; ++q4) {
    u16 pk[4];
    #pragma unroll
    for (int i = 0; i < 4; ++i) {
      const int qo = q4 * 4 + i;
      const size_t b = row0 + (size_t)qo * 64;
      const u16 raw = useMax ? mx3[b] : mn3[b];
      pk[i] = f2bf(fmaxf(fmaf(bf2f(raw), sc, sh), 0.f));
    }
    uint2 w;
    w.x = (u32)pk[0] | ((u32)pk[1] << 16);
    w.y = (u32)pk[2] | ((u32)pk[3] << 16);
    *reinterpret_cast<uint2*>(x3t + (((size_t)(n * 64 + c) * 28 + po) * 28 + q4 * 4)) = w;
  }
}

// ------------- fc1: zero-LDS MFMA K-split GEMM (56 splits x 896 k) ----------
__global__ __launch_bounds__(256)
void k_fc1(const u16* __restrict__ x3t, const float* __restrict__ w,
           float* __restrict__ partial) {
  const int kc = blockIdx.x, nt = blockIdx.y;
  const int t = threadIdx.x, lane = t & 63, wv = t >> 6;
  const int g = lane >> 4, li = lane & 15;
  const int n0 = nt * 64 + wv * 16;
  const float* wrow = w + (size_t)(n0 + li) * 50176 + kc * 896;
  const u16* xbase = x3t + kc * 896;
  f4_t acc[4];
  #pragma unroll
  for (int mf = 0; mf < 4; ++mf) acc[mf] = (f4_t)0.f;
  #pragma unroll 4
  for (int ks = 0; ks < 28; ++ks) {
    const int kb = ks * 32 + g * 8;
    const float4 wa = ldg4(wrow + kb);
    const float4 wb = ldg4(wrow + kb + 4);
    float wf[8] = {wa.x, wa.y, wa.z, wa.w, wb.x, wb.y, wb.z, wb.w};
    sh8_t hi, lo;
    #pragma unroll
    for (int j = 0; j < 8; ++j) {
      const u16 h = f2bf(wf[j]);
      hi[j] = (short)h;
      lo[j] = (short)f2bf(wf[j] - bf2f(h));
    }
    #pragma unroll
    for (int mf = 0; mf < 4; ++mf) {
      const sh8_t B = *reinterpret_cast<const sh8_t*>(
          xbase + (size_t)(mf * 16 + li) * 50176 + kb);
      acc[mf] = __builtin_amdgcn_mfma_f32_16x16x32_bf16(hi, B, acc[mf], 0, 0, 0);
      acc[mf] = __builtin_amdgcn_mfma_f32_16x16x32_bf16(lo, B, acc[mf], 0, 0, 0);
    }
  }
  float* pb = partial + (size_t)kc * 16384;
  #pragma unroll
  for (int mf = 0; mf < 4; ++mf)
    #pragma unroll
    for (int j = 0; j < 4; ++j)
      pb[(size_t)(n0 + 4 * g + j) * 64 + mf * 16 + li] = acc[mf][j];
}

__global__ __launch_bounds__(256)
void k_fc1_reduce(const float* __restrict__ partial, const float* __restrict__ b1f,
                  float* __restrict__ h1) {
  const int idx = blockIdx.x * 256 + threadIdx.x;  // 16384
  const int nn = idx >> 6, m = idx & 63;
  float a[8];
  #pragma unroll
  for (int u = 0; u < 8; ++u) a[u] = 0.f;
  #pragma unroll
  for (int k = 0; k < 56; k += 8)
    #pragma unroll
    for (int u = 0; u < 8; ++u)
      a[u] += partial[(size_t)(k + u) * 16384 + idx];
  const float s = b1f[nn] + (((a[0] + a[1]) + (a[2] + a[3])) +
                             ((a[4] + a[5]) + (a[6] + a[7])));
  h1[(size_t)m * 256 + nn] = fmaxf(s, 0.f);
}

__global__ __launch_bounds__(320)
void k_fc2(const float* __restrict__ h1, const float* __restrict__ w2f,
           const float* __restrict__ b2f, float* __restrict__ out) {
  const int t = threadIdx.x;
  const int m = t / 5, o = t - m * 5;
  const float* hr = h1 + (size_t)m * 256;
  const float* wr = w2f + (size_t)o * 256;
  float a0 = 0.f, a1 = 0.f, a2 = 0.f, a3 = 0.f;
  #pragma unroll
  for (int j = 0; j < 256; j += 16) {
    const float4 h0 = ldg4(hr + j),      w0 = ldg4(wr + j);
    const float4 h1v = ldg4(hr + j + 4),  w1v = ldg4(wr + j + 4);
    const float4 h2 = ldg4(hr + j + 8),  w2 = ldg4(wr + j + 8);
    const float4 h3 = ldg4(hr + j + 12), w3 = ldg4(wr + j + 12);
    a0 = fmaf(h0.x, w0.x, fmaf(h0.y, w0.y, fmaf(h0.z, w0.z, fmaf(h0.w, w0.w, a0))));
    a1 = fmaf(h1v.x, w1v.x, fmaf(h1v.y, w1v.y, fmaf(h1v.z, w1v.z, fmaf(h1v.w, w1v.w, a1))));
    a2 = fmaf(h2.x, w2.x, fmaf(h2.y, w2.y, fmaf(h2.z, w2.z, fmaf(h2.w, w2.w, a2))));
    a3 = fmaf(h3.x, w3.x, fmaf(h3.y, w3.y, fmaf(h3.z, w3.z, fmaf(h3.w, w3.w, a3))));
  }
  out[m * 5 + o] = b2f[o] + ((a0 + a1) + (a2 + a3));
}

// ---------------------------------------------------------------------------
extern "C" void kernel_launch(void* const* d_in, const int* in_sizes, int n_in,
                              void* d_out, int out_size, void* d_ws, size_t ws_size,
                              hipStream_t stream) {
  (void)in_sizes; (void)n_in; (void)out_size; (void)ws_size;
  const float* d   = (const float*)d_in[0];
  const float* w1  = (const float*)d_in[1];
  const float* b1  = (const float*)d_in[2];
  const float* g1  = (const float*)d_in[3];
  const float* be1 = (const float*)d_in[4];
  const float* w2  = (const float*)d_in[5];
  const float* b2  = (const float*)d_in[6];
  const float* g2  = (const float*)d_in[7];
  const float* be2 = (const float*)d_in[8];
  const float* w3  = (const float*)d_in[9];
  const float* b3  = (const float*)d_in[10];
  const float* g3  = (const float*)d_in[11];
  const float* be3 = (const float*)d_in[12];
  const float* fw1 = (const float*)d_in[13];
  const float* fb1 = (const float*)d_in[14];
  const float* fw2 = (const float*)d_in[15];
  const float* fb2 = (const float*)d_in[16];
  float* out = (float*)d_out;
  float* ws  = (float*)d_ws;

  u16* x1   = (u16*)(ws + WS_X1);
  u16* mx1  = (u16*)(ws + WS_MX1);
  u16* mn1  = (u16*)(ws + WS_MN1);
  u16* rec  = (u16*)(ws + WS_REC);   // aliases X2..MX3 (dead until conv2)
  u16* x2   = (u16*)(ws + WS_X2);
  u16* mx2  = (u16*)(ws + WS_MX2);
  u16* mn2  = (u16*)(ws + WS_MN2);
  u16* x3t  = (u16*)(ws + WS_X3T);
  u16* mx3  = (u16*)(ws + WS_MX3);
  u16* mn3  = (u16*)(ws + WS_MN3);
  u16* wt1  = (u16*)(ws + WS_WT1);
  u16* wt2  = (u16*)(ws + WS_WT2);
  u16* wt3  = (u16*)(ws + WS_WT3);
  float* p1 = ws + WS_P1;
  float* p2 = ws + WS_P2;
  float* p3 = ws + WS_P3;
  double* pd = (double*)(ws + WS_PD);
  float* st = ws + WS_ST;
  float* fcp = ws + WS_FCP;
  float* h1 = ws + WS_H1;

  k_prep_w<<<100, 256, 0, stream>>>(w1, w2, w3, wt1, wt2, wt3);
  k_prep_rec<<<3136, 256, 0, stream>>>(d, rec);
  // layer 1: single conv pass (stats + raw pool), then BN finalize + bnrelu
  k_conv1<<<dim3(15, 15, 64), 256, 0, stream>>>(rec, wt1, b1, mx1, mn1, p1);
  k_fin1<<<dim3(16, 64), 256, 0, stream>>>(p1, 57600, 900, 64, pd);
  k_fin2<<<16, 64, 0, stream>>>(pd, 64, 3240000.0, g1, be1, st + 0, st + 16);
  k_bnrelu<16, 112><<<6272, 256, 0, stream>>>(mx1, mn1, st + 0, st + 16, x1);
  // layer 2
  k_conv2<<<dim3(7, 7, 64), 256, 0, stream>>>(x1, wt2, b2, mx2, mn2, p2);
  k_fin1<<<dim3(32, 16), 256, 0, stream>>>(p2, 12544, 784, 16, pd);
  k_fin2<<<32, 64, 0, stream>>>(pd, 16, 802816.0, g2, be2, st + 32, st + 64);
  k_bnrelu<32, 56><<<3136, 256, 0, stream>>>(mx2, mn2, st + 32, st + 64, x2);
  // layer 3
  k_conv3<<<dim3(4, 7, 64), 256, 0, stream>>>(x2, wt3, b3, mx3, mn3, p3);
  k_fin1<<<dim3(64, 8), 256, 0, stream>>>(p3, 3584, 448, 8, pd);
  k_fin2<<<64, 64, 0, stream>>>(pd, 8, 200704.0, g3, be3, st + 96, st + 160);
  k_bnrelu3t<<<dim3(7, 64), 256, 0, stream>>>(mx3, mn3, st + 96, st + 160, x3t);
  // fc
  k_fc1<<<dim3(56, 4), 256, 0, stream>>>(x3t, fw1, fcp);
  k_fc1_reduce<<<64, 256, 0, stream>>>(fcp, fb1, h1);
  k_fc2<<<1, 320, 0, stream>>>(h1, fw2, fb2, out);
}

// Round 10
// 181.520 us; speedup vs baseline: 1.1206x; 1.1206x over previous
//
#include <hip/hip_runtime.h>
#include <cstdint>
#include <cstddef>

// ---------------------------------------------------------------------------
// Plant_Identifier CNN forward.
// R10: (a) sel-trick: sign(sc)=sign(gamma) known pre-stats, so conv epilogues
//      write ONE pooled buffer sel = gamma>=0 ? max : min (exact commute);
//      (b) prep_rec removed — conv1 builds hi/lo B-fragments in registers
//      from d directly (no LDS, no extra pass, no aliasing writebacks).
// conv1: bf16 MFMA, hi/lo split (fp32-exact). conv2/3: bf16 MFMA
// implicit-GEMM, fused stats + raw sel-pool. fc1: zero-LDS MFMA K-split.
// All reductions deterministic (fixed-order two-stage partials).
// ---------------------------------------------------------------------------

typedef __attribute__((ext_vector_type(8))) short sh8_t;   // 8 x bf16
typedef __attribute__((ext_vector_type(4))) float f4_t;    // mfma acc
typedef unsigned short u16;
typedef unsigned int u32;

// workspace layout (float units) — no aliasing
#define WS_X1   ((size_t)0)          // x1   bf16 [64,112,112,16] (6,422,528)
#define WS_SEL1 ((size_t)6422528)    // sel1 bf16 [64,112,112,16] (6,422,528)
#define WS_X2   ((size_t)12845056)   // x2   bf16 [64,56,56,32]   (3,211,264)
#define WS_SEL2 ((size_t)16056320)   // sel2                       (3,211,264)
#define WS_X3T  ((size_t)19267584)   // x3t  bf16 [64,64,28,28]   (1,605,632)
#define WS_SEL3 ((size_t)20873216)   // sel3 bf16 [64,28,28,64]   (1,605,632)
#define WS_WT1  ((size_t)22478848)   // 512
#define WS_WT2  ((size_t)22479360)   // 3,072
#define WS_WT3  ((size_t)22482432)   // 9,216
#define WS_P1   ((size_t)22491648)   // 16*2*57600 = 1,843,200
#define WS_P2   ((size_t)24334848)   // 32*2*12544 = 802,816
#define WS_P3   ((size_t)25137664)   // 64*2*3584  = 458,752
#define WS_PD   ((size_t)25596416)   // 4,096
#define WS_ST   ((size_t)25600512)   // 224
#define WS_FCP  ((size_t)25600736)   // 917,504
#define WS_H1   ((size_t)26518240)   // 16,384
// total 26,534,624 floats = 106.1 MB

static __device__ __forceinline__ float4 ldg4(const float* p) {
  return *reinterpret_cast<const float4*>(p);
}
static __device__ __forceinline__ float bf2f(u16 u) {
  union { u32 i; float f; } c; c.i = ((u32)u) << 16; return c.f;
}
static __device__ __forceinline__ u16 f2bf(float f) {
  union { float f; u32 i; } c; c.f = f;
  const u32 x = c.i;
  return (u16)((x + 0x7fffu + ((x >> 16) & 1u)) >> 16);   // RNE
}

// ---------------- weight prep -----------------------------------------------
__global__ __launch_bounds__(256)
void k_prep_w(const float* __restrict__ w1, const float* __restrict__ w2,
              const float* __restrict__ w3, u16* __restrict__ wt1,
              u16* __restrict__ wt2, u16* __restrict__ wt3) {
  const int t = blockIdx.x * 256 + threadIdx.x;  // 25600 total
  if (t < 1024) {
    const int half = t >> 9;
    const int u = t & 511;
    const int co = u >> 5, k = u & 31;
    const int g = k >> 3, j = k & 7;
    const int kh = g >> 1, kw = g & 1;
    const int ci = (j < 4) ? j : j - 4;
    bool active = (j != 3) && (j != 7);
    if (half == 1) active = active && (j < 4);
    float val = 0.f;
    if (active) {
      const float w = w1[((co * 3 + ci) * 2 + kh) * 2 + kw];
      const u16 h = f2bf(w);
      val = (half == 0) ? bf2f(h) : (w - bf2f(h));
    }
    wt1[t] = f2bf(val);
  } else if (t < 7168) {  // wt2 [co32][kh3][kwp4][ci16], kw=3 zero-padded
    const int u = t - 1024;
    const int ci = u & 15, kwp = (u >> 4) & 3, kh = (u >> 6) % 3, co = u / 192;
    float v = 0.f;
    if (kwp < 3) v = w2[((co * 16 + ci) * 3 + kh) * 3 + kwp];
    wt2[u] = f2bf(v);
  } else {                // wt3 [co64][kh3][kw3][ci32]
    const int u = t - 7168;
    const int ci = u & 31, kw = (u >> 5) % 3, kh = (u / 96) % 3, co = u / 288;
    wt3[u] = f2bf(w3[((co * 32 + ci) * 3 + kh) * 3 + kw]);
  }
}

// ---------------- conv1 MFMA: in-register B build, stats + sel pool ---------
// grid (15,15,64), 256 thr. 16x16 output tile of the 225x225 pre-pool map.
// lane (g,li): tap (kh=g>>1, kw=g&1). B = [hi0,hi1,hi2,0,lo0,lo1,lo2,0] built
// from 3 dword loads of d (per-channel planes), per r.
__global__ __launch_bounds__(256)
void k_conv1(const float* __restrict__ d, const u16* __restrict__ wt1,
             const float* __restrict__ b1, const float* __restrict__ g1,
             u16* __restrict__ sel1, float* __restrict__ part) {
  const int bx = blockIdx.x, by = blockIdx.y, n = blockIdx.z;
  const int ow0 = bx * 16, oh0 = by * 16;
  const int t = threadIdx.x, lane = t & 63, wv = t >> 6;
  const int g = lane >> 4, li = lane & 15;
  const int kh = g >> 1, kw = g & 1;
  const sh8_t A1 = *reinterpret_cast<const sh8_t*>(wt1 + li * 32 + g * 8);
  const sh8_t A2 = *reinterpret_cast<const sh8_t*>(wt1 + 512 + li * 32 + g * 8);
  const int iw = ow0 + li + kw - 1;
  const bool iwv = (unsigned)iw < 224u;
  const float* dbase = d + (size_t)n * 3 * 50176 + iw;
  f4_t acc[4];
  #pragma unroll
  for (int r = 0; r < 4; ++r) acc[r] = (f4_t)0.f;
  #pragma unroll
  for (int r = 0; r < 4; ++r) {
    const int ih = oh0 + wv * 4 + r + kh - 1;
    float v0 = 0.f, v1 = 0.f, v2 = 0.f;
    if (iwv && (unsigned)ih < 224u) {
      const float* p = dbase + (size_t)ih * 224;
      v0 = p[0]; v1 = p[50176]; v2 = p[100352];
    }
    const u16 h0 = f2bf(v0), h1 = f2bf(v1), h2 = f2bf(v2);
    const u16 l0 = f2bf(v0 - bf2f(h0));
    const u16 l1 = f2bf(v1 - bf2f(h1));
    const u16 l2 = f2bf(v2 - bf2f(h2));
    union { sh8_t v; u32 w[4]; } B;
    B.w[0] = (u32)h0 | ((u32)h1 << 16);
    B.w[1] = (u32)h2;
    B.w[2] = (u32)l0 | ((u32)l1 << 16);
    B.w[3] = (u32)l2;
    acc[r] = __builtin_amdgcn_mfma_f32_16x16x32_bf16(A1, B.v, acc[r], 0, 0, 0);
    acc[r] = __builtin_amdgcn_mfma_f32_16x16x32_bf16(A2, B.v, acc[r], 0, 0, 0);
  }
  // D: col = li (pixel ow), row = 4g+j (co). y = acc + bias.
  const f4_t bias = *reinterpret_cast<const f4_t*>(b1 + 4 * g);
  const f4_t gam  = *reinterpret_cast<const f4_t*>(g1 + 4 * g);
  f4_t y[4];
  #pragma unroll
  for (int r = 0; r < 4; ++r) y[r] = acc[r] + bias;
  const int ow = ow0 + li;
  // stats over valid 225x225
  {
    f4_t ssum = (f4_t)0.f, ssq = (f4_t)0.f;
    #pragma unroll
    for (int r = 0; r < 4; ++r) {
      const int oh = oh0 + wv * 4 + r;
      if (oh <= 224 && ow <= 224) { ssum += y[r]; ssq += y[r] * y[r]; }
    }
    #pragma unroll
    for (int m = 1; m < 16; m <<= 1)
      #pragma unroll
      for (int j = 0; j < 4; ++j) {
        ssum[j] += __shfl_xor(ssum[j], m);
        ssq[j]  += __shfl_xor(ssq[j], m);
      }
    if (li == 0) {
      const int slot = ((n * 15 + by) * 15 + bx) * 4 + wv;  // P1 = 57600
      #pragma unroll
      for (int j = 0; j < 4; ++j) {
        part[(size_t)((4 * g + j) * 2 + 0) * 57600 + slot] = ssum[j];
        part[(size_t)((4 * g + j) * 2 + 1) * 57600 + slot] = ssq[j];
      }
    }
  }
  // sel pool: per channel, window extremum matching sign(gamma)
  if (bx < 14 && by < 14) {
    #pragma unroll
    for (int rp = 0; rp < 2; ++rp) {
      f4_t v;
      #pragma unroll
      for (int j = 0; j < 4; ++j) {
        const float a = y[2 * rp][j], b = y[2 * rp + 1][j];
        v[j] = (gam[j] >= 0.f) ? fmaxf(a, b) : fminf(a, b);
      }
      f4_t o;
      #pragma unroll
      for (int j = 0; j < 4; ++j) o[j] = __shfl_xor(v[j], 1);
      if ((li & 1) == 0) {
        u16 pk[4];
        #pragma unroll
        for (int j = 0; j < 4; ++j)
          pk[j] = f2bf((gam[j] >= 0.f) ? fmaxf(v[j], o[j]) : fminf(v[j], o[j]));
        const int po = 8 * by + 2 * wv + rp, qo = 8 * bx + (li >> 1);
        const size_t off = ((size_t)((n * 112 + po) * 112 + qo)) * 16 + 4 * g;
        uint2 w;
        w.x = (u32)pk[0] | ((u32)pk[1] << 16);
        w.y = (u32)pk[2] | ((u32)pk[3] << 16);
        *reinterpret_cast<uint2*>(sel1 + off) = w;
      }
    }
  }
}

// ------------- BN finalize stage 1: parallel chunk reduce -------------------
__global__ __launch_bounds__(256)
void k_fin1(const float* __restrict__ part, int P, int chunk, int S,
            double* __restrict__ p2) {
  const int c = blockIdx.x, s = blockIdx.y;
  const int start = s * chunk;
  const int end = min(P, start + chunk);
  __shared__ double rs[256], rq[256];
  double accs[2];
  #pragma unroll
  for (int mom = 0; mom < 2; ++mom) {
    const float* base = part + (size_t)(c * 2 + mom) * P;
    double a0 = 0.0, a1 = 0.0, a2 = 0.0, a3 = 0.0;
    int i = start + threadIdx.x * 4;
    for (; i + 3 < end; i += 1024) {
      const float4 v = ldg4(base + i);
      a0 += v.x; a1 += v.y; a2 += v.z; a3 += v.w;
    }
    for (int j = i; j < end && j < i + 4; ++j) a0 += base[j];
    accs[mom] = (a0 + a1) + (a2 + a3);
  }
  rs[threadIdx.x] = accs[0]; rq[threadIdx.x] = accs[1];
  __syncthreads();
  for (int off = 128; off > 0; off >>= 1) {
    if (threadIdx.x < off) {
      rs[threadIdx.x] += rs[threadIdx.x + off];
      rq[threadIdx.x] += rq[threadIdx.x + off];
    }
    __syncthreads();
  }
  if (threadIdx.x == 0) {
    p2[(size_t)(c * 2 + 0) * S + s] = rs[0];
    p2[(size_t)(c * 2 + 1) * S + s] = rq[0];
  }
}

// ------------- BN finalize stage 2 ------------------------------------------
__global__ __launch_bounds__(64)
void k_fin2(const double* __restrict__ p2, int S, double count,
            const float* __restrict__ g, const float* __restrict__ bta,
            float* __restrict__ scale, float* __restrict__ shift) {
  const int c = blockIdx.x, t = threadIdx.x;
  double s = 0.0, sq = 0.0;
  if (t < S) {
    s  = p2[(size_t)(c * 2 + 0) * S + t];
    sq = p2[(size_t)(c * 2 + 1) * S + t];
  }
  #pragma unroll
  for (int m = 1; m < 64; m <<= 1) {
    s  += __shfl_xor(s, m);
    sq += __shfl_xor(sq, m);
  }
  if (t == 0) {
    const double mean = s / count;
    const double var  = sq / count - mean * mean;
    const double rstd = 1.0 / sqrt(var + 1e-5);
    const double sc = (double)g[c] * rstd;
    scale[c] = (float)sc;
    shift[c] = (float)((double)bta[c] - mean * sc);
  }
}

// ------------- bnrelu: x = relu(sc*sel + sh), NHWC ---------------------------
template<int CH, int P>
__global__ __launch_bounds__(256)
void k_bnrelu(const u16* __restrict__ sel, const float* __restrict__ scale,
              const float* __restrict__ shift, u16* __restrict__ xout) {
  constexpr int G = CH / 8;
  const int idx = blockIdx.x * 256 + threadIdx.x;
  const int cg = idx & (G - 1);
  int rest = idx / G;
  const int qo = rest % P; rest /= P;
  const int po = rest % P;
  const int n = rest / P;
  const size_t base = ((size_t)((n * P + po) * P + qo)) * CH + cg * 8;
  const int4 vs = *reinterpret_cast<const int4*>(sel + base);
  const u32* a = reinterpret_cast<const u32*>(&vs);
  u16 o[8];
  #pragma unroll
  for (int j = 0; j < 8; ++j) {
    const int c = cg * 8 + j;
    const float sc = scale[c], sh = shift[c];
    const u16 raw = (u16)(a[j >> 1] >> ((j & 1) * 16));
    o[j] = f2bf(fmaxf(fmaf(bf2f(raw), sc, sh), 0.f));
  }
  u32 pk[4];
  #pragma unroll
  for (int k = 0; k < 4; ++k) pk[k] = (u32)o[2 * k] | ((u32)o[2 * k + 1] << 16);
  *reinterpret_cast<int4*>(xout + base) = make_int4(pk[0], pk[1], pk[2], pk[3]);
}

// ------------- conv2: bf16 MFMA + stats + sel pool ---------------------------
__global__ __launch_bounds__(256)
void k_conv2(const u16* __restrict__ x1, const u16* __restrict__ wt2,
             const float* __restrict__ b2, const float* __restrict__ g2,
             u16* __restrict__ sel2, float* __restrict__ part) {
  const int ow0 = blockIdx.x * 16, oh0 = blockIdx.y * 16, n = blockIdx.z;
  const int t = threadIdx.x, lane = t & 63, wv = t >> 6;
  const int g = lane >> 4, li = lane & 15;
  __shared__ __align__(16) unsigned char tile[18 * 640];
  for (int idx = t; idx < 720; idx += 256) {
    const int rr = idx / 40, rem = idx - rr * 40, p = rem >> 1, c = rem & 1;
    const int ih = oh0 - 1 + rr, iw = ow0 - 1 + p;
    int4 v = make_int4(0, 0, 0, 0);
    if ((unsigned)ih < 112u && (unsigned)iw < 112u)
      v = *reinterpret_cast<const int4*>(x1 + ((size_t)((n * 112 + ih) * 112 + iw) * 16 + c * 8));
    *reinterpret_cast<int4*>(tile + ((rr * 640 + p * 32 + c * 16) ^ (((p >> 2) & 1) << 4))) = v;
  }
  sh8_t W[2][3][2];
  #pragma unroll
  for (int cot = 0; cot < 2; ++cot)
    #pragma unroll
    for (int kh = 0; kh < 3; ++kh)
      #pragma unroll
      for (int m = 0; m < 2; ++m)
        W[cot][kh][m] = *reinterpret_cast<const sh8_t*>(
            wt2 + ((cot * 16 + li) * 192 + kh * 64 + m * 32 + g * 8));
  f4_t acc[4][2];
  #pragma unroll
  for (int r = 0; r < 4; ++r) { acc[r][0] = (f4_t)0.f; acc[r][1] = (f4_t)0.f; }
  __syncthreads();
  const int rowb = 4 * wv;
  #pragma unroll
  for (int ihr = 0; ihr < 6; ++ihr) {
    const int row = rowb + ihr;
    #pragma unroll
    for (int m = 0; m < 2; ++m) {
      const int p = li + 2 * m + (g >> 1);
      const sh8_t B = *reinterpret_cast<const sh8_t*>(
          tile + ((row * 640 + p * 32 + (g & 1) * 16) ^ (((p >> 2) & 1) << 4)));
      #pragma unroll
      for (int kh = 0; kh < 3; ++kh) {
        const int r = ihr - kh;
        if (r >= 0 && r < 4) {
          acc[r][0] = __builtin_amdgcn_mfma_f32_16x16x32_bf16(W[0][kh][m], B, acc[r][0], 0, 0, 0);
          acc[r][1] = __builtin_amdgcn_mfma_f32_16x16x32_bf16(W[1][kh][m], B, acc[r][1], 0, 0, 0);
        }
      }
    }
  }
  f4_t bias[2], gam[2], ssum[2], ssq[2];
  bias[0] = *reinterpret_cast<const f4_t*>(b2 + 4 * g);
  bias[1] = *reinterpret_cast<const f4_t*>(b2 + 16 + 4 * g);
  gam[0]  = *reinterpret_cast<const f4_t*>(g2 + 4 * g);
  gam[1]  = *reinterpret_cast<const f4_t*>(g2 + 16 + 4 * g);
  ssum[0] = (f4_t)0.f; ssum[1] = (f4_t)0.f; ssq[0] = (f4_t)0.f; ssq[1] = (f4_t)0.f;
  #pragma unroll
  for (int r = 0; r < 4; ++r)
    #pragma unroll
    for (int cot = 0; cot < 2; ++cot) {
      acc[r][cot] += bias[cot];
      ssum[cot] += acc[r][cot];
      ssq[cot] += acc[r][cot] * acc[r][cot];
    }
  #pragma unroll
  for (int msk = 1; msk < 16; msk <<= 1)
    #pragma unroll
    for (int cot = 0; cot < 2; ++cot)
      #pragma unroll
      for (int j = 0; j < 4; ++j) {
        ssum[cot][j] += __shfl_xor(ssum[cot][j], msk);
        ssq[cot][j]  += __shfl_xor(ssq[cot][j], msk);
      }
  if (li == 0) {
    const int slot = (((n * 7 + (int)blockIdx.y) * 7 + (int)blockIdx.x)) * 4 + wv;  // 12544
    #pragma unroll
    for (int cot = 0; cot < 2; ++cot)
      #pragma unroll
      for (int j = 0; j < 4; ++j) {
        const int co = cot * 16 + 4 * g + j;
        part[(size_t)(co * 2 + 0) * 12544 + slot] = ssum[cot][j];
        part[(size_t)(co * 2 + 1) * 12544 + slot] = ssq[cot][j];
      }
  }
  const int pob = 8 * (int)blockIdx.y + 2 * wv;
  const int qo = 8 * (int)blockIdx.x + (li >> 1);
  #pragma unroll
  for (int rp = 0; rp < 2; ++rp)
    #pragma unroll
    for (int cot = 0; cot < 2; ++cot) {
      f4_t v;
      #pragma unroll
      for (int j = 0; j < 4; ++j) {
        const float a = acc[2 * rp][cot][j], b = acc[2 * rp + 1][cot][j];
        v[j] = (gam[cot][j] >= 0.f) ? fmaxf(a, b) : fminf(a, b);
      }
      f4_t o;
      #pragma unroll
      for (int j = 0; j < 4; ++j) o[j] = __shfl_xor(v[j], 1);
      if ((li & 1) == 0) {
        u16 pk[4];
        #pragma unroll
        for (int j = 0; j < 4; ++j)
          pk[j] = f2bf((gam[cot][j] >= 0.f) ? fmaxf(v[j], o[j]) : fminf(v[j], o[j]));
        const size_t off = ((size_t)((n * 56 + pob + rp) * 56 + qo)) * 32 + cot * 16 + 4 * g;
        uint2 w;
        w.x = (u32)pk[0] | ((u32)pk[1] << 16);
        w.y = (u32)pk[2] | ((u32)pk[3] << 16);
        *reinterpret_cast<uint2*>(sel2 + off) = w;
      }
    }
}

// ------------- conv3: bf16 MFMA + stats + sel pool ---------------------------
__global__ __launch_bounds__(256)
void k_conv3(const u16* __restrict__ x2, const u16* __restrict__ wt3,
             const float* __restrict__ b3, const float* __restrict__ g3,
             u16* __restrict__ sel3, float* __restrict__ part) {
  const int ow0 = blockIdx.x * 16, oh0 = blockIdx.y * 8, n = blockIdx.z;
  const int t = threadIdx.x, lane = t & 63, wv = t >> 6;
  const int rh = wv & 1, ch = wv >> 1;
  const int g = lane >> 4, li = lane & 15;
  __shared__ __align__(16) unsigned char tile[10 * 1152];
  for (int idx = t; idx < 720; idx += 256) {
    const int rr = idx / 72, rem = idx - rr * 72, p = rem >> 2, c = rem & 3;
    const int ih = oh0 - 1 + rr, iw = ow0 - 1 + p;
    int4 v = make_int4(0, 0, 0, 0);
    if ((unsigned)ih < 56u && (unsigned)iw < 56u)
      v = *reinterpret_cast<const int4*>(x2 + ((size_t)((n * 56 + ih) * 56 + iw) * 32 + c * 8));
    *reinterpret_cast<int4*>(tile + ((rr * 1152 + p * 64 + c * 16) ^ (((p >> 1) & 3) << 4))) = v;
  }
  sh8_t W[2][3][3];
  #pragma unroll
  for (int c2 = 0; c2 < 2; ++c2)
    #pragma unroll
    for (int kh = 0; kh < 3; ++kh)
      #pragma unroll
      for (int kw = 0; kw < 3; ++kw)
        W[c2][kh][kw] = *reinterpret_cast<const sh8_t*>(
            wt3 + ((size_t)(ch * 32 + c2 * 16 + li) * 288 + (kh * 3 + kw) * 32 + g * 8));
  f4_t acc[4][2];
  #pragma unroll
  for (int r = 0; r < 4; ++r) { acc[r][0] = (f4_t)0.f; acc[r][1] = (f4_t)0.f; }
  __syncthreads();
  const int rowb = 4 * rh;
  #pragma unroll
  for (int ihr = 0; ihr < 6; ++ihr) {
    const int row = rowb + ihr;
    #pragma unroll
    for (int kw = 0; kw < 3; ++kw) {
      const int p = li + kw;
      const sh8_t B = *reinterpret_cast<const sh8_t*>(
          tile + ((row * 1152 + p * 64 + g * 16) ^ (((p >> 1) & 3) << 4)));
      #pragma unroll
      for (int kh = 0; kh < 3; ++kh) {
        const int r = ihr - kh;
        if (r >= 0 && r < 4) {
          acc[r][0] = __builtin_amdgcn_mfma_f32_16x16x32_bf16(W[0][kh][kw], B, acc[r][0], 0, 0, 0);
          acc[r][1] = __builtin_amdgcn_mfma_f32_16x16x32_bf16(W[1][kh][kw], B, acc[r][1], 0, 0, 0);
        }
      }
    }
  }
  const int ow = ow0 + li;
  const bool valid = ow < 56;
  f4_t bias[2], gam[2], ssum[2], ssq[2];
  bias[0] = *reinterpret_cast<const f4_t*>(b3 + ch * 32 + 4 * g);
  bias[1] = *reinterpret_cast<const f4_t*>(b3 + ch * 32 + 16 + 4 * g);
  gam[0]  = *reinterpret_cast<const f4_t*>(g3 + ch * 32 + 4 * g);
  gam[1]  = *reinterpret_cast<const f4_t*>(g3 + ch * 32 + 16 + 4 * g);
  ssum[0] = (f4_t)0.f; ssum[1] = (f4_t)0.f; ssq[0] = (f4_t)0.f; ssq[1] = (f4_t)0.f;
  #pragma unroll
  for (int r = 0; r < 4; ++r)
    #pragma unroll
    for (int c2 = 0; c2 < 2; ++c2) {
      acc[r][c2] += bias[c2];
      if (valid) {
        ssum[c2] += acc[r][c2];
        ssq[c2] += acc[r][c2] * acc[r][c2];
      }
    }
  #pragma unroll
  for (int msk = 1; msk < 16; msk <<= 1)
    #pragma unroll
    for (int c2 = 0; c2 < 2; ++c2)
      #pragma unroll
      for (int j = 0; j < 4; ++j) {
        ssum[c2][j] += __shfl_xor(ssum[c2][j], msk);
        ssq[c2][j]  += __shfl_xor(ssq[c2][j], msk);
      }
  if (li == 0) {
    const int slot = (((n * 7 + (int)blockIdx.y) * 4 + (int)blockIdx.x)) * 2 + rh;  // 3584
    #pragma unroll
    for (int c2 = 0; c2 < 2; ++c2)
      #pragma unroll
      for (int j = 0; j < 4; ++j) {
        const int co = ch * 32 + c2 * 16 + 4 * g + j;
        part[(size_t)(co * 2 + 0) * 3584 + slot] = ssum[c2][j];
        part[(size_t)(co * 2 + 1) * 3584 + slot] = ssq[c2][j];
      }
  }
  const int pob = 4 * (int)blockIdx.y + 2 * rh;
  const int qo = 8 * (int)blockIdx.x + (li >> 1);
  #pragma unroll
  for (int rp = 0; rp < 2; ++rp)
    #pragma unroll
    for (int c2 = 0; c2 < 2; ++c2) {
      f4_t v;
      #pragma unroll
      for (int j = 0; j < 4; ++j) {
        const float a = acc[2 * rp][c2][j], b = acc[2 * rp + 1][c2][j];
        v[j] = (gam[c2][j] >= 0.f) ? fmaxf(a, b) : fminf(a, b);
      }
      f4_t o;
      #pragma unroll
      for (int j = 0; j < 4; ++j) o[j] = __shfl_xor(v[j], 1);
      if (((li & 1) == 0) && (ow + 1 < 56)) {
        u16 pk[4];
        #pragma unroll
        for (int j = 0; j < 4; ++j)
          pk[j] = f2bf((gam[c2][j] >= 0.f) ? fmaxf(v[j], o[j]) : fminf(v[j], o[j]));
        const size_t off = ((size_t)((n * 28 + pob + rp) * 28 + qo)) * 64 + ch * 32 + c2 * 16 + 4 * g;
        uint2 w;
        w.x = (u32)pk[0] | ((u32)pk[1] << 16);
        w.y = (u32)pk[2] | ((u32)pk[3] << 16);
        *reinterpret_cast<uint2*>(sel3 + off) = w;
      }
    }
}

// ------------- bnrelu3 + NHWC->NCHW transpose for fc1 -----------------------
__global__ __launch_bounds__(256)
void k_bnrelu3t(const u16* __restrict__ sel3, const float* __restrict__ scale,
                const float* __restrict__ shift, u16* __restrict__ x3t) {
  const int n = blockIdx.y;
  const int c = threadIdx.x & 63, pq = threadIdx.x >> 6;
  const int po = blockIdx.x * 4 + pq;
  const float sc = scale[c], sh = shift[c];
  const size_t row0 = ((size_t)(n * 28 + po)) * 28 * 64 + c;
  #pragma unroll
  for (int q4 = 0; q4 < 7; ++q4) {
    u16 pk[4];
    #pragma unroll
    for (int i = 0; i < 4; ++i) {
      const int qo = q4 * 4 + i;
      const u16 raw = sel3[row0 + (size_t)qo * 64];
      pk[i] = f2bf(fmaxf(fmaf(bf2f(raw), sc, sh), 0.f));
    }
    uint2 w;
    w.x = (u32)pk[0] | ((u32)pk[1] << 16);
    w.y = (u32)pk[2] | ((u32)pk[3] << 16);
    *reinterpret_cast<uint2*>(x3t + (((size_t)(n * 64 + c) * 28 + po) * 28 + q4 * 4)) = w;
  }
}

// ------------- fc1: zero-LDS MFMA K-split GEMM (56 splits x 896 k) ----------
__global__ __launch_bounds__(256)
void k_fc1(const u16* __restrict__ x3t, const float* __restrict__ w,
           float* __restrict__ partial) {
  const int kc = blockIdx.x, nt = blockIdx.y;
  const int t = threadIdx.x, lane = t & 63, wv = t >> 6;
  const int g = lane >> 4, li = lane & 15;
  const int n0 = nt * 64 + wv * 16;
  const float* wrow = w + (size_t)(n0 + li) * 50176 + kc * 896;
  const u16* xbase = x3t + kc * 896;
  f4_t acc[4];
  #pragma unroll
  for (int mf = 0; mf < 4; ++mf) acc[mf] = (f4_t)0.f;
  #pragma unroll 4
  for (int ks = 0; ks < 28; ++ks) {
    const int kb = ks * 32 + g * 8;
    const float4 wa = ldg4(wrow + kb);
    const float4 wb = ldg4(wrow + kb + 4);
    float wf[8] = {wa.x, wa.y, wa.z, wa.w, wb.x, wb.y, wb.z, wb.w};
    sh8_t hi, lo;
    #pragma unroll
    for (int j = 0; j < 8; ++j) {
      const u16 h = f2bf(wf[j]);
      hi[j] = (short)h;
      lo[j] = (short)f2bf(wf[j] - bf2f(h));
    }
    #pragma unroll
    for (int mf = 0; mf < 4; ++mf) {
      const sh8_t B = *reinterpret_cast<const sh8_t*>(
          xbase + (size_t)(mf * 16 + li) * 50176 + kb);
      acc[mf] = __builtin_amdgcn_mfma_f32_16x16x32_bf16(hi, B, acc[mf], 0, 0, 0);
      acc[mf] = __builtin_amdgcn_mfma_f32_16x16x32_bf16(lo, B, acc[mf], 0, 0, 0);
    }
  }
  float* pb = partial + (size_t)kc * 16384;
  #pragma unroll
  for (int mf = 0; mf < 4; ++mf)
    #pragma unroll
    for (int j = 0; j < 4; ++j)
      pb[(size_t)(n0 + 4 * g + j) * 64 + mf * 16 + li] = acc[mf][j];
}

__global__ __launch_bounds__(256)
void k_fc1_reduce(const float* __restrict__ partial, const float* __restrict__ b1f,
                  float* __restrict__ h1) {
  const int idx = blockIdx.x * 256 + threadIdx.x;  // 16384
  const int nn = idx >> 6, m = idx & 63;
  float a[8];
  #pragma unroll
  for (int u = 0; u < 8; ++u) a[u] = 0.f;
  #pragma unroll
  for (int k = 0; k < 56; k += 8)
    #pragma unroll
    for (int u = 0; u < 8; ++u)
      a[u] += partial[(size_t)(k + u) * 16384 + idx];
  const float s = b1f[nn] + (((a[0] + a[1]) + (a[2] + a[3])) +
                             ((a[4] + a[5]) + (a[6] + a[7])));
  h1[(size_t)m * 256 + nn] = fmaxf(s, 0.f);
}

__global__ __launch_bounds__(320)
void k_fc2(const float* __restrict__ h1, const float* __restrict__ w2f,
           const float* __restrict__ b2f, float* __restrict__ out) {
  const int t = threadIdx.x;
  const int m = t / 5, o = t - m * 5;
  const float* hr = h1 + (size_t)m * 256;
  const float* wr = w2f + (size_t)o * 256;
  float a0 = 0.f, a1 = 0.f, a2 = 0.f, a3 = 0.f;
  #pragma unroll
  for (int j = 0; j < 256; j += 16) {
    const float4 h0 = ldg4(hr + j),      w0 = ldg4(wr + j);
    const float4 h1v = ldg4(hr + j + 4),  w1v = ldg4(wr + j + 4);
    const float4 h2 = ldg4(hr + j + 8),  w2 = ldg4(wr + j + 8);
    const float4 h3 = ldg4(hr + j + 12), w3 = ldg4(wr + j + 12);
    a0 = fmaf(h0.x, w0.x, fmaf(h0.y, w0.y, fmaf(h0.z, w0.z, fmaf(h0.w, w0.w, a0))));
    a1 = fmaf(h1v.x, w1v.x, fmaf(h1v.y, w1v.y, fmaf(h1v.z, w1v.z, fmaf(h1v.w, w1v.w, a1))));
    a2 = fmaf(h2.x, w2.x, fmaf(h2.y, w2.y, fmaf(h2.z, w2.z, fmaf(h2.w, w2.w, a2))));
    a3 = fmaf(h3.x, w3.x, fmaf(h3.y, w3.y, fmaf(h3.z, w3.z, fmaf(h3.w, w3.w, a3))));
  }
  out[m * 5 + o] = b2f[o] + ((a0 + a1) + (a2 + a3));
}

// ---------------------------------------------------------------------------
extern "C" void kernel_launch(void* const* d_in, const int* in_sizes, int n_in,
                              void* d_out, int out_size, void* d_ws, size_t ws_size,
                              hipStream_t stream) {
  (void)in_sizes; (void)n_in; (void)out_size; (void)ws_size;
  const float* d   = (const float*)d_in[0];
  const float* w1  = (const float*)d_in[1];
  const float* b1  = (const float*)d_in[2];
  const float* g1  = (const float*)d_in[3];
  const float* be1 = (const float*)d_in[4];
  const float* w2  = (const float*)d_in[5];
  const float* b2  = (const float*)d_in[6];
  const float* g2  = (const float*)d_in[7];
  const float* be2 = (const float*)d_in[8];
  const float* w3  = (const float*)d_in[9];
  const float* b3  = (const float*)d_in[10];
  const float* g3  = (const float*)d_in[11];
  const float* be3 = (const float*)d_in[12];
  const float* fw1 = (const float*)d_in[13];
  const float* fb1 = (const float*)d_in[14];
  const float* fw2 = (const float*)d_in[15];
  const float* fb2 = (const float*)d_in[16];
  float* out = (float*)d_out;
  float* ws  = (float*)d_ws;

  u16* x1   = (u16*)(ws + WS_X1);
  u16* sel1 = (u16*)(ws + WS_SEL1);
  u16* x2   = (u16*)(ws + WS_X2);
  u16* sel2 = (u16*)(ws + WS_SEL2);
  u16* x3t  = (u16*)(ws + WS_X3T);
  u16* sel3 = (u16*)(ws + WS_SEL3);
  u16* wt1  = (u16*)(ws + WS_WT1);
  u16* wt2  = (u16*)(ws + WS_WT2);
  u16* wt3  = (u16*)(ws + WS_WT3);
  float* p1 = ws + WS_P1;
  float* p2 = ws + WS_P2;
  float* p3 = ws + WS_P3;
  double* pd = (double*)(ws + WS_PD);
  float* st = ws + WS_ST;
  float* fcp = ws + WS_FCP;
  float* h1 = ws + WS_H1;

  k_prep_w<<<100, 256, 0, stream>>>(w1, w2, w3, wt1, wt2, wt3);
  // layer 1: conv (stats + sel pool), BN finalize, bnrelu
  k_conv1<<<dim3(15, 15, 64), 256, 0, stream>>>(d, wt1, b1, g1, sel1, p1);
  k_fin1<<<dim3(16, 64), 256, 0, stream>>>(p1, 57600, 900, 64, pd);
  k_fin2<<<16, 64, 0, stream>>>(pd, 64, 3240000.0, g1, be1, st + 0, st + 16);
  k_bnrelu<16, 112><<<6272, 256, 0, stream>>>(sel1, st + 0, st + 16, x1);
  // layer 2
  k_conv2<<<dim3(7, 7, 64), 256, 0, stream>>>(x1, wt2, b2, g2, sel2, p2);
  k_fin1<<<dim3(32, 16), 256, 0, stream>>>(p2, 12544, 784, 16, pd);
  k_fin2<<<32, 64, 0, stream>>>(pd, 16, 802816.0, g2, be2, st + 32, st + 64);
  k_bnrelu<32, 56><<<3136, 256, 0, stream>>>(sel2, st + 32, st + 64, x2);
  // layer 3
  k_conv3<<<dim3(4, 7, 64), 256, 0, stream>>>(x2, wt3, b3, g3, sel3, p3);
  k_fin1<<<dim3(64, 8), 256, 0, stream>>>(p3, 3584, 448, 8, pd);
  k_fin2<<<64, 64, 0, stream>>>(pd, 8, 200704.0, g3, be3, st + 96, st + 160);
  k_bnrelu3t<<<dim3(7, 64), 256, 0, stream>>>(sel3, st + 96, st + 160, x3t);
  // fc
  k_fc1<<<dim3(56, 4), 256, 0, stream>>>(x3t, fw1, fcp);
  k_fc1_reduce<<<64, 256, 0, stream>>>(fcp, fb1, h1);
  k_fc2<<<1, 320, 0, stream>>>(h1, fw2, fb2, out);
}